// Round 3
// baseline (309.043 us; speedup 1.0000x reference)
//
#include <hip/hip_runtime.h>

// bf16 MFMA fragment types (gfx950): A/B = 8 bf16 (4 VGPR), C/D = 4 fp32
typedef __attribute__((ext_vector_type(8))) short bf16x8;
typedef __attribute__((ext_vector_type(4))) float f32x4;
typedef __attribute__((ext_vector_type(2))) unsigned int u32x2;
typedef __attribute__((ext_vector_type(4))) unsigned int u32x4;

#define LDSTR 136            // W1^T LDS leading dim (shorts): 128 + 8 pad
#define TPW 8                // 16-edge tiles per wave; 512 edges per block
#define QD 3                 // gather prefetch queue depth (tiles in flight)

// f32 -> bf16 round-to-nearest-even
static __device__ __forceinline__ unsigned int pack2bf(float x, float y) {
  unsigned int ux = __builtin_bit_cast(unsigned int, x);
  ux += 0x7fffu + ((ux >> 16) & 1u);
  unsigned int uy = __builtin_bit_cast(unsigned int, y);
  uy += 0x7fffu + ((uy >> 16) & 1u);
  return (ux >> 16) | (uy & 0xffff0000u);
}
static __device__ __forceinline__ unsigned short f2bf_s(float x) {
  unsigned int ux = __builtin_bit_cast(unsigned int, x);
  ux += 0x7fffu + ((ux >> 16) & 1u);
  return (unsigned short)(ux >> 16);
}

// ---- pass 0: node table f32 -> bf16 into d_ws (row = 128 B = 1 cache line) ----
__global__ __launch_bounds__(256) void cvt_nodes(const float4* __restrict__ in,
                                                 u32x2* __restrict__ out, int n4) {
  int i = blockIdx.x * 256 + threadIdx.x;
  if (i < n4) {
    float4 v = in[i];
    u32x2 p;
    p[0] = pack2bf(v.x, v.y);
    p[1] = pack2bf(v.z, v.w);
    out[i] = p;
  }
}

// ---- main: deep-pipelined bf16 row gather -> MFMA MLP (weights from LDS) ----
__global__ __launch_bounds__(256, 4) void edge_mlp_bf16(
    const unsigned short* __restrict__ nodes_bf,  // [N,64] bf16, row = 128 B
    const int*   __restrict__ src,
    const int*   __restrict__ dst,
    const float* __restrict__ W1,   // [128,64] f32 row-major
    const float* __restrict__ b1,
    const float* __restrict__ W2,   // [64]
    const float* __restrict__ b2,
    float*       __restrict__ out,  // [E]
    int E)
{
  __shared__ unsigned short ls_w1t[64 * LDSTR];  // W1^T [n][k] bf16
  __shared__ float ls_b1[64];
  __shared__ float ls_w2[64];

  const int tid  = threadIdx.x;
  const int wave = tid >> 6;
  const int lane = tid & 63;
  const int l15  = lane & 15;
  const int quad = lane >> 4;

  for (int i = tid; i < 64 * 128; i += 256) {
    int n = i >> 7, k = i & 127;
    ls_w1t[n * LDSTR + k] = f2bf_s(W1[k * 64 + n]);
  }
  if (tid < 64) { ls_b1[tid] = b1[tid]; ls_w2[tid] = W2[tid]; }
  __syncthreads();

  // Weight fragment accessor (re-read from LDS each tile; frees 64 VGPRs
  // for the gather prefetch queue). WF(tn,s) = W1T[n=tn*16+l15][k=s*32+quad*8..+7]
  const unsigned short* wbase = &ls_w1t[l15 * LDSTR + quad * 8];
#define WF(tn, s) (*(const bf16x8*)(wbase + (tn) * (16 * LDSTR) + (s) * 32))

  float myb1[4], myw2[4];
  #pragma unroll
  for (int tn = 0; tn < 4; ++tn) {
    myb1[tn] = ls_b1[tn * 16 + l15];
    myw2[tn] = ls_w2[tn * 16 + l15];
  }
  const float b2v = b2[0];

  const int wave_base = blockIdx.x * (TPW * 64) + wave * (TPW * 16);

  // Precompute per-tile gather byte offsets (row*128 + quad*16); 32-bit.
  int soff[TPW], doff[TPW];
  #pragma unroll
  for (int t = 0; t < TPW; ++t) {
    int e = wave_base + t * 16 + l15;
    e = (e < E) ? e : 0;
    soff[t] = src[e] * 128 + quad * 16;
    doff[t] = dst[e] * 128 + quad * 16;
  }

  const char* nb = (const char*)nodes_bf;

  // Prefetch queue: QD tiles in flight, 4 loads each (src lo/hi, dst lo/hi).
  bf16x8 q[QD][4];
#define GATHER(t, slot)                                         \
  do {                                                          \
    q[slot][0] = *(const bf16x8*)(nb + soff[t]);                \
    q[slot][1] = *(const bf16x8*)(nb + soff[t] + 64);           \
    q[slot][2] = *(const bf16x8*)(nb + doff[t]);                \
    q[slot][3] = *(const bf16x8*)(nb + doff[t] + 64);           \
  } while (0)

  GATHER(0, 0);
  GATHER(1, 1);
  GATHER(2, 2);

  #pragma unroll
  for (int t = 0; t < TPW; ++t) {
    const int slot = t % QD;
    const int tile_base = wave_base + t * 16;

    f32x4 acc[4];
    #pragma unroll
    for (int tn = 0; tn < 4; ++tn) acc[tn] = (f32x4){0.f, 0.f, 0.f, 0.f};

    // k-blocks: s=0,1 -> src halves; s=2,3 -> dst halves (concat layout)
    #pragma unroll
    for (int s = 0; s < 4; ++s) {
      bf16x8 a = q[slot][s];
      #pragma unroll
      for (int tn = 0; tn < 4; ++tn)
        acc[tn] = __builtin_amdgcn_mfma_f32_16x16x32_bf16(a, WF(tn, s), acc[tn], 0, 0, 0);
    }

    // Refill this slot with tile t+QD (loads fly while we finish epilogue
    // and the next tiles compute — vmcnt never drains to 0 mid-loop).
    if (t + QD < TPW) GATHER(t + QD, slot);

    if (tile_base < E) {
      // Layer 2: D layout col=l15 (channel n), row=quad*4+r (edge)
      #pragma unroll
      for (int r = 0; r < 4; ++r) {
        float p = 0.f;
        #pragma unroll
        for (int tn = 0; tn < 4; ++tn) {
          float h = acc[tn][r] + myb1[tn];
          h = fmaxf(h, 0.f);
          p = __builtin_fmaf(h, myw2[tn], p);
        }
        p += __shfl_xor(p, 1);
        p += __shfl_xor(p, 2);
        p += __shfl_xor(p, 4);
        p += __shfl_xor(p, 8);
        if (l15 == 0) out[tile_base + quad * 4 + r] = p + b2v;
      }
    }
  }
#undef GATHER
#undef WF
}

// ---- fallback (f32 gathers, weights in registers) if ws too small ----
static __device__ __forceinline__ bf16x8 make_afrag(float4 lo, float4 hi) {
  u32x4 p;
  p[0] = pack2bf(lo.x, lo.y);
  p[1] = pack2bf(lo.z, lo.w);
  p[2] = pack2bf(hi.x, hi.y);
  p[3] = pack2bf(hi.z, hi.w);
  return __builtin_bit_cast(bf16x8, p);
}

__global__ __launch_bounds__(256) void edge_mlp_f32(
    const float* __restrict__ nodes_emb, const int* __restrict__ src,
    const int* __restrict__ dst, const float* __restrict__ W1,
    const float* __restrict__ b1, const float* __restrict__ W2,
    const float* __restrict__ b2, float* __restrict__ out, int E)
{
  __shared__ unsigned short ls_w1t[64 * LDSTR];
  __shared__ float ls_b1[64];
  __shared__ float ls_w2[64];
  const int tid = threadIdx.x, wave = tid >> 6, lane = tid & 63;
  const int l15 = lane & 15, quad = lane >> 4;
  for (int i = tid; i < 64 * 128; i += 256) {
    int n = i >> 7, k = i & 127;
    ls_w1t[n * LDSTR + k] = f2bf_s(W1[k * 64 + n]);
  }
  if (tid < 64) { ls_b1[tid] = b1[tid]; ls_w2[tid] = W2[tid]; }
  __syncthreads();
  bf16x8 bfrag[4][4];
  #pragma unroll
  for (int tn = 0; tn < 4; ++tn)
    #pragma unroll
    for (int s = 0; s < 4; ++s)
      bfrag[tn][s] = *(const bf16x8*)&ls_w1t[(tn * 16 + l15) * LDSTR + s * 32 + quad * 8];
  float myb1[4], myw2[4];
  #pragma unroll
  for (int tn = 0; tn < 4; ++tn) { myb1[tn] = ls_b1[tn*16+l15]; myw2[tn] = ls_w2[tn*16+l15]; }
  const float b2v = b2[0];
  const int wave_base = blockIdx.x * (TPW * 64) + wave * (TPW * 16);
  #pragma unroll 1
  for (int t = 0; t < TPW; ++t) {
    const int tile_base = wave_base + t * 16;
    if (tile_base >= E) break;
    const int e = tile_base + l15;
    const int si = src[e], di = dst[e];
    const float* srow = nodes_emb + (long long)si * 64 + quad * 8;
    const float* drow = nodes_emb + (long long)di * 64 + quad * 8;
    float4 v0 = *(const float4*)(srow),      v1 = *(const float4*)(srow + 4);
    float4 v2 = *(const float4*)(srow + 32), v3 = *(const float4*)(srow + 36);
    float4 v4 = *(const float4*)(drow),      v5 = *(const float4*)(drow + 4);
    float4 v6 = *(const float4*)(drow + 32), v7 = *(const float4*)(drow + 36);
    bf16x8 afr[4] = {make_afrag(v0,v1), make_afrag(v2,v3), make_afrag(v4,v5), make_afrag(v6,v7)};
    f32x4 acc[4];
    #pragma unroll
    for (int tn = 0; tn < 4; ++tn) acc[tn] = (f32x4){0.f,0.f,0.f,0.f};
    #pragma unroll
    for (int s = 0; s < 4; ++s)
      #pragma unroll
      for (int tn = 0; tn < 4; ++tn)
        acc[tn] = __builtin_amdgcn_mfma_f32_16x16x32_bf16(afr[s], bfrag[tn][s], acc[tn], 0, 0, 0);
    #pragma unroll
    for (int r = 0; r < 4; ++r) {
      float p = 0.f;
      #pragma unroll
      for (int tn = 0; tn < 4; ++tn) {
        float h = acc[tn][r] + myb1[tn];
        h = fmaxf(h, 0.f);
        p = __builtin_fmaf(h, myw2[tn], p);
      }
      p += __shfl_xor(p, 1); p += __shfl_xor(p, 2);
      p += __shfl_xor(p, 4); p += __shfl_xor(p, 8);
      if (l15 == 0) out[tile_base + quad * 4 + r] = p + b2v;
    }
  }
}

extern "C" void kernel_launch(void* const* d_in, const int* in_sizes, int n_in,
                              void* d_out, int out_size, void* d_ws, size_t ws_size,
                              hipStream_t stream) {
  const float* nodes_emb = (const float*)d_in[0];
  const int*   src       = (const int*)d_in[1];
  const int*   dst       = (const int*)d_in[2];
  const float* W1        = (const float*)d_in[3];
  const float* b1        = (const float*)d_in[4];
  const float* W2        = (const float*)d_in[5];
  const float* b2        = (const float*)d_in[6];
  float* out = (float*)d_out;

  const int E = in_sizes[1];
  const int nodes_elems = in_sizes[0];               // 150000*64
  const int epb = TPW * 64;                          // 512 edges / block
  const int blocks = (E + epb - 1) / epb;
  const size_t need = (size_t)nodes_elems * 2;       // bf16 table bytes

  if (ws_size >= need) {
    const int n4 = nodes_elems / 4;
    hipLaunchKernelGGL(cvt_nodes, dim3((n4 + 255) / 256), dim3(256), 0, stream,
                       (const float4*)nodes_emb, (u32x2*)d_ws, n4);
    hipLaunchKernelGGL(edge_mlp_bf16, dim3(blocks), dim3(256), 0, stream,
                       (const unsigned short*)d_ws, src, dst, W1, b1, W2, b2, out, E);
  } else {
    hipLaunchKernelGGL(edge_mlp_f32, dim3(blocks), dim3(256), 0, stream,
                       nodes_emb, src, dst, W1, b1, W2, b2, out, E);
  }
}

// Round 4
// 219.253 us; speedup vs baseline: 1.4095x; 1.4095x over previous
//
#include <hip/hip_runtime.h>

// bf16 MFMA fragment types (gfx950): A/B = 8 bf16 (4 VGPR), C/D = 4 fp32
typedef __attribute__((ext_vector_type(8))) short bf16x8;
typedef __attribute__((ext_vector_type(4))) float f32x4;
typedef __attribute__((ext_vector_type(2))) unsigned int u32x2;
typedef __attribute__((ext_vector_type(4))) unsigned int u32x4;

#define LDSTR 136            // W1^T LDS leading dim (shorts): 128 + 8 pad
#define TPW 8                // 16-edge tiles per wave; 512 edges per block

// f32 -> bf16 round-to-nearest-even
static __device__ __forceinline__ unsigned int pack2bf(float x, float y) {
  unsigned int ux = __builtin_bit_cast(unsigned int, x);
  ux += 0x7fffu + ((ux >> 16) & 1u);
  unsigned int uy = __builtin_bit_cast(unsigned int, y);
  uy += 0x7fffu + ((uy >> 16) & 1u);
  return (ux >> 16) | (uy & 0xffff0000u);
}
static __device__ __forceinline__ unsigned short f2bf_s(float x) {
  unsigned int ux = __builtin_bit_cast(unsigned int, x);
  ux += 0x7fffu + ((ux >> 16) & 1u);
  return (unsigned short)(ux >> 16);
}

// ---- pass 0: node table f32 -> bf16 into d_ws (row = 128 B = 1 cache line) ----
__global__ __launch_bounds__(256) void cvt_nodes(const float4* __restrict__ in,
                                                 u32x2* __restrict__ out, int n4) {
  int i = blockIdx.x * 256 + threadIdx.x;
  if (i < n4) {
    float4 v = in[i];
    u32x2 p;
    p[0] = pack2bf(v.x, v.y);
    p[1] = pack2bf(v.z, v.w);
    out[i] = p;
  }
}

// ---- main: depth-2 named-register pipelined gather -> MFMA MLP ----
// All pipeline state in NAMED registers (r3's mod-indexed arrays went to
// scratch: WRITE_SIZE 7.9->138 MB). Manual unroll via macros.
__global__ __launch_bounds__(256, 3) void edge_mlp_bf16(
    const unsigned short* __restrict__ nodes_bf,  // [N,64] bf16, row = 128 B
    const int*   __restrict__ src,
    const int*   __restrict__ dst,
    const float* __restrict__ W1,   // [128,64] f32 row-major
    const float* __restrict__ b1,
    const float* __restrict__ W2,   // [64]
    const float* __restrict__ b2,
    float*       __restrict__ out,  // [E]
    int E)
{
  __shared__ unsigned short ls_w1t[64 * LDSTR];  // W1^T [n][k] bf16
  __shared__ float ls_b1[64];
  __shared__ float ls_w2[64];

  const int tid  = threadIdx.x;
  const int wave = tid >> 6;
  const int lane = tid & 63;
  const int l15  = lane & 15;
  const int quad = lane >> 4;

  for (int i = tid; i < 64 * 128; i += 256) {
    int n = i >> 7, k = i & 127;
    ls_w1t[n * LDSTR + k] = f2bf_s(W1[k * 64 + n]);
  }
  if (tid < 64) { ls_b1[tid] = b1[tid]; ls_w2[tid] = W2[tid]; }
  __syncthreads();

  // Hoist weight fragments to registers (proven r2 codegen):
  // bfrag[tn][s] = W1T[n=tn*16+l15][k=s*32+quad*8 .. +7]
  bf16x8 bfrag[4][4];
  #pragma unroll
  for (int tn = 0; tn < 4; ++tn)
    #pragma unroll
    for (int s = 0; s < 4; ++s)
      bfrag[tn][s] = *(const bf16x8*)&ls_w1t[(tn * 16 + l15) * LDSTR + s * 32 + quad * 8];

  float myb1[4], myw2[4];
  #pragma unroll
  for (int tn = 0; tn < 4; ++tn) {
    myb1[tn] = ls_b1[tn * 16 + l15];
    myw2[tn] = ls_w2[tn * 16 + l15];
  }
  const float b2v = b2[0];

  const int wave_base = blockIdx.x * (TPW * 64) + wave * (TPW * 16);
  const int qoff = quad * 16;                 // byte offset of this quad's sliver
  const char* nb = (const char*)nodes_bf;

  // Per-tile gather byte offsets as NAMED scalars (bf16 row = 128 B).
#define IDX(T)                                              \
  int e##T = wave_base + (T) * 16 + l15;                    \
  e##T = (e##T < E) ? e##T : 0;                             \
  const int so##T = src[e##T] * 128 + qoff;                 \
  const int dd##T = dst[e##T] * 128 + qoff;

  IDX(0) IDX(1) IDX(2) IDX(3) IDX(4) IDX(5) IDX(6) IDX(7)

#define GATHER(T, A0, A1, A2, A3)                           \
  A0 = *(const bf16x8*)(nb + so##T);                        \
  A1 = *(const bf16x8*)(nb + so##T + 64);                   \
  A2 = *(const bf16x8*)(nb + dd##T);                        \
  A3 = *(const bf16x8*)(nb + dd##T + 64);

#define COMPUTE(T, A0, A1, A2, A3)                                             \
  do {                                                                         \
    f32x4 ac0 = {0.f,0.f,0.f,0.f}, ac1 = {0.f,0.f,0.f,0.f};                    \
    f32x4 ac2 = {0.f,0.f,0.f,0.f}, ac3 = {0.f,0.f,0.f,0.f};                    \
    ac0 = __builtin_amdgcn_mfma_f32_16x16x32_bf16(A0, bfrag[0][0], ac0, 0,0,0);\
    ac1 = __builtin_amdgcn_mfma_f32_16x16x32_bf16(A0, bfrag[1][0], ac1, 0,0,0);\
    ac2 = __builtin_amdgcn_mfma_f32_16x16x32_bf16(A0, bfrag[2][0], ac2, 0,0,0);\
    ac3 = __builtin_amdgcn_mfma_f32_16x16x32_bf16(A0, bfrag[3][0], ac3, 0,0,0);\
    ac0 = __builtin_amdgcn_mfma_f32_16x16x32_bf16(A1, bfrag[0][1], ac0, 0,0,0);\
    ac1 = __builtin_amdgcn_mfma_f32_16x16x32_bf16(A1, bfrag[1][1], ac1, 0,0,0);\
    ac2 = __builtin_amdgcn_mfma_f32_16x16x32_bf16(A1, bfrag[2][1], ac2, 0,0,0);\
    ac3 = __builtin_amdgcn_mfma_f32_16x16x32_bf16(A1, bfrag[3][1], ac3, 0,0,0);\
    ac0 = __builtin_amdgcn_mfma_f32_16x16x32_bf16(A2, bfrag[0][2], ac0, 0,0,0);\
    ac1 = __builtin_amdgcn_mfma_f32_16x16x32_bf16(A2, bfrag[1][2], ac1, 0,0,0);\
    ac2 = __builtin_amdgcn_mfma_f32_16x16x32_bf16(A2, bfrag[2][2], ac2, 0,0,0);\
    ac3 = __builtin_amdgcn_mfma_f32_16x16x32_bf16(A2, bfrag[3][2], ac3, 0,0,0);\
    ac0 = __builtin_amdgcn_mfma_f32_16x16x32_bf16(A3, bfrag[0][3], ac0, 0,0,0);\
    ac1 = __builtin_amdgcn_mfma_f32_16x16x32_bf16(A3, bfrag[1][3], ac1, 0,0,0);\
    ac2 = __builtin_amdgcn_mfma_f32_16x16x32_bf16(A3, bfrag[2][3], ac2, 0,0,0);\
    ac3 = __builtin_amdgcn_mfma_f32_16x16x32_bf16(A3, bfrag[3][3], ac3, 0,0,0);\
    const int tb = wave_base + (T) * 16;                                       \
    if (tb < E) {                                                              \
      _Pragma("unroll")                                                        \
      for (int r = 0; r < 4; ++r) {                                            \
        float h0 = fmaxf(ac0[r] + myb1[0], 0.f);                               \
        float h1 = fmaxf(ac1[r] + myb1[1], 0.f);                               \
        float h2 = fmaxf(ac2[r] + myb1[2], 0.f);                               \
        float h3 = fmaxf(ac3[r] + myb1[3], 0.f);                               \
        float p = h0 * myw2[0];                                                \
        p = __builtin_fmaf(h1, myw2[1], p);                                    \
        p = __builtin_fmaf(h2, myw2[2], p);                                    \
        p = __builtin_fmaf(h3, myw2[3], p);                                    \
        p += __shfl_xor(p, 1);                                                 \
        p += __shfl_xor(p, 2);                                                 \
        p += __shfl_xor(p, 4);                                                 \
        p += __shfl_xor(p, 8);                                                 \
        if (l15 == 0) out[tb + quad * 4 + r] = p + b2v;                        \
      }                                                                        \
    }                                                                          \
  } while (0)

  bf16x8 a0, a1, a2, a3, b0, b1r, b2r, b3, c0, c1, c2, c3;

  GATHER(0, a0, a1, a2, a3)
  GATHER(1, b0, b1r, b2r, b3)
  GATHER(2, c0, c1, c2, c3)

  COMPUTE(0, a0, a1, a2, a3);  GATHER(3, a0, a1, a2, a3)
  COMPUTE(1, b0, b1r, b2r, b3); GATHER(4, b0, b1r, b2r, b3)
  COMPUTE(2, c0, c1, c2, c3);  GATHER(5, c0, c1, c2, c3)
  COMPUTE(3, a0, a1, a2, a3);  GATHER(6, a0, a1, a2, a3)
  COMPUTE(4, b0, b1r, b2r, b3); GATHER(7, b0, b1r, b2r, b3)
  COMPUTE(5, c0, c1, c2, c3);
  COMPUTE(6, a0, a1, a2, a3);
  COMPUTE(7, b0, b1r, b2r, b3);

#undef IDX
#undef GATHER
#undef COMPUTE
}

// ---- fallback (f32 gathers, weights in registers) if ws too small ----
static __device__ __forceinline__ bf16x8 make_afrag(float4 lo, float4 hi) {
  u32x4 p;
  p[0] = pack2bf(lo.x, lo.y);
  p[1] = pack2bf(lo.z, lo.w);
  p[2] = pack2bf(hi.x, hi.y);
  p[3] = pack2bf(hi.z, hi.w);
  return __builtin_bit_cast(bf16x8, p);
}

__global__ __launch_bounds__(256) void edge_mlp_f32(
    const float* __restrict__ nodes_emb, const int* __restrict__ src,
    const int* __restrict__ dst, const float* __restrict__ W1,
    const float* __restrict__ b1, const float* __restrict__ W2,
    const float* __restrict__ b2, float* __restrict__ out, int E)
{
  __shared__ unsigned short ls_w1t[64 * LDSTR];
  __shared__ float ls_b1[64];
  __shared__ float ls_w2[64];
  const int tid = threadIdx.x, wave = tid >> 6, lane = tid & 63;
  const int l15 = lane & 15, quad = lane >> 4;
  for (int i = tid; i < 64 * 128; i += 256) {
    int n = i >> 7, k = i & 127;
    ls_w1t[n * LDSTR + k] = f2bf_s(W1[k * 64 + n]);
  }
  if (tid < 64) { ls_b1[tid] = b1[tid]; ls_w2[tid] = W2[tid]; }
  __syncthreads();
  bf16x8 bfrag[4][4];
  #pragma unroll
  for (int tn = 0; tn < 4; ++tn)
    #pragma unroll
    for (int s = 0; s < 4; ++s)
      bfrag[tn][s] = *(const bf16x8*)&ls_w1t[(tn * 16 + l15) * LDSTR + s * 32 + quad * 8];
  float myb1[4], myw2[4];
  #pragma unroll
  for (int tn = 0; tn < 4; ++tn) { myb1[tn] = ls_b1[tn*16+l15]; myw2[tn] = ls_w2[tn*16+l15]; }
  const float b2v = b2[0];
  const int wave_base = blockIdx.x * (TPW * 64) + wave * (TPW * 16);
  #pragma unroll 1
  for (int t = 0; t < TPW; ++t) {
    const int tile_base = wave_base + t * 16;
    if (tile_base >= E) break;
    const int e = tile_base + l15;
    const int si = src[e], di = dst[e];
    const float* srow = nodes_emb + (long long)si * 64 + quad * 8;
    const float* drow = nodes_emb + (long long)di * 64 + quad * 8;
    float4 v0 = *(const float4*)(srow),      v1 = *(const float4*)(srow + 4);
    float4 v2 = *(const float4*)(srow + 32), v3 = *(const float4*)(srow + 36);
    float4 v4 = *(const float4*)(drow),      v5 = *(const float4*)(drow + 4);
    float4 v6 = *(const float4*)(drow + 32), v7 = *(const float4*)(drow + 36);
    bf16x8 afr[4] = {make_afrag(v0,v1), make_afrag(v2,v3), make_afrag(v4,v5), make_afrag(v6,v7)};
    f32x4 acc[4];
    #pragma unroll
    for (int tn = 0; tn < 4; ++tn) acc[tn] = (f32x4){0.f,0.f,0.f,0.f};
    #pragma unroll
    for (int s = 0; s < 4; ++s)
      #pragma unroll
      for (int tn = 0; tn < 4; ++tn)
        acc[tn] = __builtin_amdgcn_mfma_f32_16x16x32_bf16(afr[s], bfrag[tn][s], acc[tn], 0, 0, 0);
    #pragma unroll
    for (int r = 0; r < 4; ++r) {
      float p = 0.f;
      #pragma unroll
      for (int tn = 0; tn < 4; ++tn) {
        float h = acc[tn][r] + myb1[tn];
        h = fmaxf(h, 0.f);
        p = __builtin_fmaf(h, myw2[tn], p);
      }
      p += __shfl_xor(p, 1); p += __shfl_xor(p, 2);
      p += __shfl_xor(p, 4); p += __shfl_xor(p, 8);
      if (l15 == 0) out[tile_base + quad * 4 + r] = p + b2v;
    }
  }
}

extern "C" void kernel_launch(void* const* d_in, const int* in_sizes, int n_in,
                              void* d_out, int out_size, void* d_ws, size_t ws_size,
                              hipStream_t stream) {
  const float* nodes_emb = (const float*)d_in[0];
  const int*   src       = (const int*)d_in[1];
  const int*   dst       = (const int*)d_in[2];
  const float* W1        = (const float*)d_in[3];
  const float* b1        = (const float*)d_in[4];
  const float* W2        = (const float*)d_in[5];
  const float* b2        = (const float*)d_in[6];
  float* out = (float*)d_out;

  const int E = in_sizes[1];
  const int nodes_elems = in_sizes[0];               // 150000*64
  const int epb = TPW * 64;                          // 512 edges / block
  const int blocks = (E + epb - 1) / epb;
  const size_t need = (size_t)nodes_elems * 2;       // bf16 table bytes

  if (ws_size >= need) {
    const int n4 = nodes_elems / 4;
    hipLaunchKernelGGL(cvt_nodes, dim3((n4 + 255) / 256), dim3(256), 0, stream,
                       (const float4*)nodes_emb, (u32x2*)d_ws, n4);
    hipLaunchKernelGGL(edge_mlp_bf16, dim3(blocks), dim3(256), 0, stream,
                       (const unsigned short*)d_ws, src, dst, W1, b1, W2, b2, out, E);
  } else {
    hipLaunchKernelGGL(edge_mlp_f32, dim3(blocks), dim3(256), 0, stream,
                       nodes_emb, src, dst, W1, b1, W2, b2, out, E);
  }
}